// Round 2
// baseline (103.935 us; speedup 1.0000x reference)
//
#include <hip/hip_runtime.h>

// Channel_mixing8: per-pixel (B*H*W = 32768) over C=64 channels:
//   attn[i,j] = softmax_i( v[i]*k[j] );  out[i] = sum_j attn[i,j] * q[j]
// Restructured: S_j = sum_i exp(v_i k_j);  out_i = sum_j (q_j / S_j) * exp(v_i k_j)
// No max-subtraction: |v*k| <= ~30 for N(0,1) inputs, fp32 exp is safe.
//
// R2 mapping: 8 lanes per pixel (ICH=8 i-channels per lane) -> 4096 waves
// = 4 waves/SIMD (R1's quad mapping gave only 2 waves/SIMD, 17% occupancy,
// latency-bound at 45us). S_j reduced across 8 lanes: 2x DPP quad_perm
// (xor1, xor2) + 1x ds_swizzle (xor4).

constexpr int C    = 64;
constexpr int HW   = 128 * 128;          // 16384 = 1<<14
constexpr int NPIX = 2 * HW;             // 32768
constexpr int ICH  = 8;                  // i-channels per thread (C / 8)
#define LOG2E 1.4426950408889634f

__device__ __forceinline__ float quad_xor1_add(float x) {
  int xi = __builtin_bit_cast(int, x);
  int yi = __builtin_amdgcn_update_dpp(0, xi, 0xB1, 0xF, 0xF, true); // [1,0,3,2]
  return x + __builtin_bit_cast(float, yi);
}
__device__ __forceinline__ float quad_xor2_add(float x) {
  int xi = __builtin_bit_cast(int, x);
  int yi = __builtin_amdgcn_update_dpp(0, xi, 0x4E, 0xF, 0xF, true); // [2,3,0,1]
  return x + __builtin_bit_cast(float, yi);
}
__device__ __forceinline__ float xor4_add(float x) {
  int xi = __builtin_bit_cast(int, x);
  // ds_swizzle BitMode: offset = (xor_mask<<10)|(or<<5)|and = (4<<10)|0x1F
  int yi = __builtin_amdgcn_ds_swizzle(xi, 0x101F);
  return x + __builtin_bit_cast(float, yi);
}

__global__ __launch_bounds__(256) void channel_mixing_kernel(
    const float* __restrict__ q,    // x
    const float* __restrict__ kk,   // y
    const float* __restrict__ v,    // z
    float* __restrict__ out) {
  const int lane = threadIdx.x & 63;
  const int wave = blockIdx.x * 4 + (threadIdx.x >> 6);
  const int p    = lane >> 3;       // pixel within wave [0,8)
  const int ig   = lane & 7;        // i-group [0,8)
  const int pix  = wave * 8 + p;

  // [b,c,h,w]: elem(b,c,phw) = b*(C*HW) + c*HW + phw ; C*HW = 1<<20
  const int base  = ((pix >> 14) << 20) | (pix & (HW - 1));   // c = 0
  const int cbase = base + (ig << 17);                        // c = ig*8

  // Load my 8 v-channels, pre-scaled by log2(e) so exp(x)=exp2(x*log2e).
  float vv[ICH];
#pragma unroll
  for (int ii = 0; ii < ICH; ++ii)
    vv[ii] = v[cbase + (ii << 14)] * LOG2E;

  float acc[ICH];
#pragma unroll
  for (int ii = 0; ii < ICH; ++ii) acc[ii] = 0.0f;

#pragma unroll 8
  for (int j = 0; j < C; ++j) {
    const float kj = kk[base + (j << 14)];
    const float qj = q[base + (j << 14)];

    float e[ICH];
#pragma unroll
    for (int ii = 0; ii < ICH; ++ii)
      e[ii] = __builtin_amdgcn_exp2f(vv[ii] * kj);

    // tree-sum of 8 partials (depth 3), then cross-lane for full S_j
    float s0 = (e[0] + e[1]) + (e[2] + e[3]);
    float s1 = (e[4] + e[5]) + (e[6] + e[7]);
    float S  = s0 + s1;
    S = quad_xor1_add(S);
    S = quad_xor2_add(S);
    S = xor4_add(S);

    const float w = qj * __builtin_amdgcn_rcpf(S);
#pragma unroll
    for (int ii = 0; ii < ICH; ++ii) acc[ii] += w * e[ii];
  }

#pragma unroll
  for (int ii = 0; ii < ICH; ++ii)
    out[cbase + (ii << 14)] = acc[ii];
}

extern "C" void kernel_launch(void* const* d_in, const int* in_sizes, int n_in,
                              void* d_out, int out_size, void* d_ws, size_t ws_size,
                              hipStream_t stream) {
  const float* q  = (const float*)d_in[0];  // x
  const float* kk = (const float*)d_in[1];  // y
  const float* v  = (const float*)d_in[2];  // z
  float* out = (float*)d_out;

  // 32768 px / (8 px per wave * 4 waves per block) = 1024 blocks
  dim3 grid(NPIX / 32);
  dim3 block(256);
  channel_mixing_kernel<<<grid, block, 0, stream>>>(q, kk, v, out);
}

// Round 3
// 92.897 us; speedup vs baseline: 1.1188x; 1.1188x over previous
//
#include <hip/hip_runtime.h>

// Channel_mixing8: per-pixel (B*H*W = 32768) over C=64 channels:
//   attn[i,j] = softmax_i( v[i]*k[j] );  out[i] = sum_j attn[i,j] * q[j]
// Restructured: S_j = sum_i exp(v_i k_j);  out_i = sum_j (q_j / S_j) * exp(v_i k_j)
//
// R3: R1/R2 were per-wave latency-serialized (one vmcnt(0) + swizzle chain per
// j; time independent of wave count). Fix: (a) stage k/q tiles in LDS once per
// block, (b) process j in tiles of 8 so the 8 S-reduction chains (DPP/swizzle/
// rcp) overlap and the 64 exps per tile give pure trans-pipe ILP.
// Mapping: block = 256 thr = 4 waves = 32 px; lane = p*8+ig; ig owns 8 i-chan.

constexpr int C    = 64;
constexpr int HW   = 128 * 128;          // 16384 = 1<<14
constexpr int NPIX = 2 * HW;             // 32768
constexpr int ICH  = 8;                  // i-channels per lane
constexpr int JT   = 8;                  // j-tile
constexpr int LSTR = 68;                 // LDS row stride (floats): 272B, 16B-aligned
#define LOG2E 1.4426950408889634f

__device__ __forceinline__ float quad_xor1_add(float x) {
  int xi = __builtin_bit_cast(int, x);
  int yi = __builtin_amdgcn_update_dpp(0, xi, 0xB1, 0xF, 0xF, true); // [1,0,3,2]
  return x + __builtin_bit_cast(float, yi);
}
__device__ __forceinline__ float quad_xor2_add(float x) {
  int xi = __builtin_bit_cast(int, x);
  int yi = __builtin_amdgcn_update_dpp(0, xi, 0x4E, 0xF, 0xF, true); // [2,3,0,1]
  return x + __builtin_bit_cast(float, yi);
}
__device__ __forceinline__ float xor4_add(float x) {
  int xi = __builtin_bit_cast(int, x);
  int yi = __builtin_amdgcn_ds_swizzle(xi, 0x101F);  // xor lane^4, BitMode
  return x + __builtin_bit_cast(float, yi);
}

__global__ __launch_bounds__(256, 4) void channel_mixing_kernel(
    const float* __restrict__ q,    // x
    const float* __restrict__ kk,   // y
    const float* __restrict__ v,    // z
    float* __restrict__ out) {
  __shared__ __align__(16) float lds_k[32 * LSTR];
  __shared__ __align__(16) float lds_q[32 * LSTR];

  const int t        = threadIdx.x;
  const int pixblock = blockIdx.x * 32;               // 32 px per block
  // [b,c,h,w]: elem(b,c,phw) = (b<<20) + (c<<14) + phw ; blocks never straddle b
  const int gbase = ((pixblock >> 14) << 20) | (pixblock & (HW - 1)); // c=0, px=0

  // ---- stage k,q for all 32 px x 64 j into LDS (coalesced 128B rows) ----
#pragma unroll
  for (int rep = 0; rep < 8; ++rep) {
    const int idx = rep * 256 + t;        // 0..2047
    const int j   = idx >> 5;             // 0..63
    const int px  = idx & 31;
    lds_k[px * LSTR + j] = kk[gbase + (j << 14) + px];
    lds_q[px * LSTR + j] = q [gbase + (j << 14) + px];
  }

  const int lane = t & 63;
  const int p    = lane >> 3;                         // pixel-in-wave [0,8)
  const int ig   = lane & 7;                          // i-group [0,8)
  const int px   = (t >> 6) * 8 + p;                  // pixel-in-block [0,32)
  const int base  = gbase + px;                       // c=0 element of my pixel
  const int cbase = base + (ig << 17);                // c = ig*8

  // my 8 v-channels, pre-scaled so exp(x)=exp2(x*log2e)
  float vv[ICH];
#pragma unroll
  for (int ii = 0; ii < ICH; ++ii)
    vv[ii] = v[cbase + (ii << 14)] * LOG2E;

  float acc[ICH];
#pragma unroll
  for (int ii = 0; ii < ICH; ++ii) acc[ii] = 0.0f;

  __syncthreads();

  const float* lkp = &lds_k[px * LSTR];
  const float* lqp = &lds_q[px * LSTR];

#pragma unroll 1
  for (int jt = 0; jt < C / JT; ++jt) {
    float kx[JT], qx[JT];
    *(float4*)&kx[0] = *(const float4*)&lkp[jt * JT];      // ds_read_b128
    *(float4*)&kx[4] = *(const float4*)&lkp[jt * JT + 4];
    *(float4*)&qx[0] = *(const float4*)&lqp[jt * JT];
    *(float4*)&qx[4] = *(const float4*)&lqp[jt * JT + 4];

    // 64 independent exps: trans-pipe ILP
    float e[JT][ICH];
#pragma unroll
    for (int jj = 0; jj < JT; ++jj)
#pragma unroll
      for (int ii = 0; ii < ICH; ++ii)
        e[jj][ii] = __builtin_amdgcn_exp2f(vv[ii] * kx[jj]);

    // 8 batched S-reductions; cross-lane latencies overlap
    float S[JT];
#pragma unroll
    for (int jj = 0; jj < JT; ++jj) {
      float s0 = (e[jj][0] + e[jj][1]) + (e[jj][2] + e[jj][3]);
      float s1 = (e[jj][4] + e[jj][5]) + (e[jj][6] + e[jj][7]);
      S[jj] = s0 + s1;
    }
#pragma unroll
    for (int jj = 0; jj < JT; ++jj) S[jj] = quad_xor1_add(S[jj]);
#pragma unroll
    for (int jj = 0; jj < JT; ++jj) S[jj] = quad_xor2_add(S[jj]);
#pragma unroll
    for (int jj = 0; jj < JT; ++jj) S[jj] = xor4_add(S[jj]);

#pragma unroll
    for (int jj = 0; jj < JT; ++jj) {
      const float w = qx[jj] * __builtin_amdgcn_rcpf(S[jj]);
#pragma unroll
      for (int ii = 0; ii < ICH; ++ii) acc[ii] += w * e[jj][ii];
    }
  }

#pragma unroll
  for (int ii = 0; ii < ICH; ++ii)
    out[cbase + (ii << 14)] = acc[ii];
}

extern "C" void kernel_launch(void* const* d_in, const int* in_sizes, int n_in,
                              void* d_out, int out_size, void* d_ws, size_t ws_size,
                              hipStream_t stream) {
  const float* q  = (const float*)d_in[0];  // x
  const float* kk = (const float*)d_in[1];  // y
  const float* v  = (const float*)d_in[2];  // z
  float* out = (float*)d_out;

  dim3 grid(NPIX / 32);   // 1024 blocks x 256 threads, 32 px per block
  dim3 block(256);
  channel_mixing_kernel<<<grid, block, 0, stream>>>(q, kk, v, out);
}